// Round 13
// baseline (478.244 us; speedup 1.0000x reference)
//
#include <hip/hip_runtime.h>
#include <math.h>

#define HDIM 128
#define G4 512  // 4*H
#define TS 36   // GEMM LDS row stride (floats)

typedef float vf4 __attribute__((ext_vector_type(4)));
typedef unsigned short u16x8 __attribute__((ext_vector_type(8)));

__device__ __forceinline__ float sigm(float v) { return 1.0f / (1.0f + __expf(-v)); }
__device__ __forceinline__ float ftanh(float v) {
    return 1.0f - 2.0f / (__expf(2.0f * v) + 1.0f);
}
__device__ __forceinline__ float dot4(vf4 a, vf4 b) {
    return a.x * b.x + a.y * b.y + a.z * b.z + a.w * b.w;
}
__device__ __forceinline__ vf4 ldnt4(const float* p) {
    return __builtin_nontemporal_load((const vf4*)p);
}
__device__ __forceinline__ unsigned short f2bf(float f) {  // RTNE
    unsigned u = __float_as_uint(f);
    u += 0x7fff + ((u >> 16) & 1);
    return (unsigned short)(u >> 16);
}
__device__ __forceinline__ float bf2f(unsigned short h) {
    return __uint_as_float(((unsigned)h) << 16);
}

// ---- setup: Wc prep + segment starts + gh0 (= Wc_h . h0, h0 from biases)
__global__ __launch_bounds__(256) void k_setup(const float* __restrict__ W_ih,
                                               const float* __restrict__ W_hh,
                                               const float* __restrict__ b_ih,
                                               const float* __restrict__ b_hh,
                                               const int* __restrict__ batch_vec, int N, int B,
                                               float* __restrict__ Wc, int* __restrict__ seg_start,
                                               float* __restrict__ gh0) {
    __shared__ float h0s[HDIM];
    int t = blockIdx.x * 256 + threadIdx.x;
    if (blockIdx.x < 2) {
        if (threadIdx.x < HDIM) {
            int hid = threadIdx.x;
            float bi = b_ih[hid] + b_hh[hid];
            float bg = b_ih[2 * HDIM + hid] + b_hh[2 * HDIM + hid];
            float bo = b_ih[3 * HDIM + hid] + b_hh[3 * HDIM + hid];
            float c0 = sigm(bi) * ftanh(bg);
            h0s[hid] = sigm(bo) * ftanh(c0);
        }
        __syncthreads();
        if (t < G4) {
            float s = 0.0f;
#pragma unroll
            for (int k = 0; k < HDIM; k += 4) {
                vf4 wi = *(const vf4*)(W_ih + (size_t)t * 256 + k);
                vf4 wh = *(const vf4*)(W_hh + (size_t)t * HDIM + k);
                s += (wi.x + wh.x) * h0s[k] + (wi.y + wh.y) * h0s[k + 1] +
                     (wi.z + wh.z) * h0s[k + 2] + (wi.w + wh.w) * h0s[k + 3];
            }
            gh0[t] = s;
        }
    }
    if (t < G4 * 2 * HDIM) {
        int g = t >> 8;
        int k = t & 255;
        float w = W_ih[g * 256 + k];
        if (k < HDIM) w += W_hh[g * HDIM + k];
        Wc[t] = w;
    }
    if (t <= B) {
        int lo = 0, hi = N;
        while (lo < hi) {
            int mid = (lo + hi) >> 1;
            if (batch_vec[mid] < t) lo = mid + 1; else hi = mid;
        }
        seg_start[t] = lo;
    }
}

#define UPD(m_, d_, ra_, rb_, p_, xa_, xb_)  \
    {                                        \
        float mn_ = fmaxf(m_, p_);           \
        float sc_ = __expf(m_ - mn_);        \
        float pe_ = __expf(p_ - mn_);        \
        d_ = d_ * sc_ + pe_;                 \
        ra_ = ra_ * sc_ + pe_ * xa_;         \
        rb_ = rb_ * sc_ + pe_ * xb_;         \
        m_ = mn_;                            \
    }

#define SHFL16(p_)                  \
    p_ += __shfl_xor(p_, 1, 64);    \
    p_ += __shfl_xor(p_, 2, 64);    \
    p_ += __shfl_xor(p_, 4, 64);    \
    p_ += __shfl_xor(p_, 8, 64);

struct AttState {
    float m0, d0, m1, d1;
    vf4 ra0, rb0, ra1, rb1;
};

__device__ __forceinline__ void init_state(AttState& st) {
    st.m0 = 0.f; st.d0 = 0.f; st.m1 = 0.f; st.d1 = 0.f;
    st.ra0 = vf4{0.f, 0.f, 0.f, 0.f}; st.rb0 = vf4{0.f, 0.f, 0.f, 0.f};
    st.ra1 = vf4{0.f, 0.f, 0.f, 0.f}; st.rb1 = vf4{0.f, 0.f, 0.f, 0.f};
}

__device__ __forceinline__ void compute4(const vf4 xa[4], const vf4 xb[4], int baserow, int e,
                                         vf4 qa, vf4 qb, AttState& st) {
    float p[4];
#pragma unroll
    for (int t = 0; t < 4; ++t) p[t] = dot4(xa[t], qa) + dot4(xb[t], qb);
    SHFL16(p[0]) SHFL16(p[1]) SHFL16(p[2]) SHFL16(p[3])
#pragma unroll
    for (int t = 0; t < 4; ++t)
        if (baserow + t >= e) p[t] = -1e30f;
    UPD(st.m0, st.d0, st.ra0, st.rb0, p[0], xa[0], xb[0])
    UPD(st.m1, st.d1, st.ra1, st.rb1, p[1], xa[1], xb[1])
    UPD(st.m0, st.d0, st.ra0, st.rb0, p[2], xa[2], xb[2])
    UPD(st.m1, st.d1, st.ra1, st.rb1, p[3], xa[3], xb[3])
}

__device__ __forceinline__ void finish_state(AttState& st, float* dst) {
    float M = fmaxf(st.m0, st.m1);
    float w0 = __expf(st.m0 - M), w1 = __expf(st.m1 - M);
    float d = st.d0 * w0 + st.d1 * w1;
    vf4 ra = st.ra0 * w0 + st.ra1 * w1;
    vf4 rb = st.rb0 * w0 + st.rb1 * w1;
    float inv = (d > 0.0f) ? 1.0f / d : 0.0f;
    *(vf4*)dst = ra * inv;
    *(vf4*)(dst + 4) = rb * inv;
}

// segment geometry for quarter-per-segment layout (4 segs/wave, 16/block)
__device__ __forceinline__ int seg_of_block(int bid, int nblk, int rev, int wave, int quarter) {
    int q8 = nblk >> 3, r8 = nblk & 7;
    int xcd = bid & 7, pos = bid >> 3;
    int nb = (xcd < r8 ? xcd * (q8 + 1) : r8 * (q8 + 1) + (xcd - r8) * q8) + pos;
    if (rev) nb = nblk - 1 - nb;
    return nb * 16 + wave * 4 + quarter;
}

// ---- pass 1: fp32 x attention + fused bf16 conversion; q0 from biases.
// Quarter-per-segment, 2-stage software pipeline (R9-proven form).
__global__ __launch_bounds__(256) void k_attn_cvt(const float* __restrict__ x,
                                                  unsigned short* __restrict__ x16,
                                                  const float* __restrict__ b_ih,
                                                  const float* __restrict__ b_hh,
                                                  const int* __restrict__ seg_start,
                                                  float* __restrict__ r_out, int B) {
    int wave = threadIdx.x >> 6;
    int lane = threadIdx.x & 63;
    int l16 = lane & 15;
    int quarter = lane >> 4;
    int seg = seg_of_block(blockIdx.x, gridDim.x, 0, wave, quarter);
    int seg_c = min(seg, B - 1);
    int s = seg_start[seg_c], e = seg_start[seg_c + 1];
    if (seg >= B) { s = 0; e = 0; }

    vf4 qa, qb;
    {  // q0 from biases (step-0 LSTM with h=c=0)
        int c = l16 * 8;
        vf4 bi0 = *(const vf4*)(b_ih + c) + *(const vf4*)(b_hh + c);
        vf4 bi1 = *(const vf4*)(b_ih + c + 4) + *(const vf4*)(b_hh + c + 4);
        vf4 bg0 = *(const vf4*)(b_ih + 2 * HDIM + c) + *(const vf4*)(b_hh + 2 * HDIM + c);
        vf4 bg1 = *(const vf4*)(b_ih + 2 * HDIM + c + 4) + *(const vf4*)(b_hh + 2 * HDIM + c + 4);
        vf4 bo0 = *(const vf4*)(b_ih + 3 * HDIM + c) + *(const vf4*)(b_hh + 3 * HDIM + c);
        vf4 bo1 = *(const vf4*)(b_ih + 3 * HDIM + c + 4) + *(const vf4*)(b_hh + 3 * HDIM + c + 4);
#pragma unroll
        for (int j = 0; j < 4; ++j) {
            float c0 = sigm(bi0[j]) * ftanh(bg0[j]);
            qa[j] = sigm(bo0[j]) * ftanh(c0);
            float c1 = sigm(bi1[j]) * ftanh(bg1[j]);
            qb[j] = sigm(bo1[j]) * ftanh(c1);
        }
    }

    int iters = (e - s + 3) >> 2;
    iters = max(iters, __shfl_xor(iters, 16, 64));
    iters = max(iters, __shfl_xor(iters, 32, 64));
    iters = max(iters, 1);

    AttState st;
    init_state(st);

    vf4 ca[4], cb[4];
#pragma unroll
    for (int t = 0; t < 4; ++t) {
        int rl = max(min(s + t, e - 1), 0);
        const float* xr = x + (size_t)rl * HDIM + l16 * 8;
        ca[t] = ldnt4(xr);
        cb[t] = ldnt4(xr + 4);
    }
    int base = s;
#pragma unroll 1
    for (int j = 1; j < iters; ++j) {
        vf4 na[4], nb[4];
#pragma unroll
        for (int t = 0; t < 4; ++t) {
            int rl = max(min(s + 4 * j + t, e - 1), 0);
            const float* xr = x + (size_t)rl * HDIM + l16 * 8;
            na[t] = ldnt4(xr);
            nb[t] = ldnt4(xr + 4);
        }
#pragma unroll
        for (int t = 0; t < 4; ++t) {
            if (base + t < e) {
                u16x8 cv;
                cv[0] = f2bf(ca[t].x); cv[1] = f2bf(ca[t].y); cv[2] = f2bf(ca[t].z); cv[3] = f2bf(ca[t].w);
                cv[4] = f2bf(cb[t].x); cv[5] = f2bf(cb[t].y); cv[6] = f2bf(cb[t].z); cv[7] = f2bf(cb[t].w);
                *(u16x8*)(x16 + (size_t)(base + t) * HDIM + l16 * 8) = cv;
            }
        }
        compute4(ca, cb, base, e, qa, qb, st);
#pragma unroll
        for (int t = 0; t < 4; ++t) { ca[t] = na[t]; cb[t] = nb[t]; }
        base += 4;
    }
#pragma unroll
    for (int t = 0; t < 4; ++t) {
        if (base + t < e) {
            u16x8 cv;
            cv[0] = f2bf(ca[t].x); cv[1] = f2bf(ca[t].y); cv[2] = f2bf(ca[t].z); cv[3] = f2bf(ca[t].w);
            cv[4] = f2bf(cb[t].x); cv[5] = f2bf(cb[t].y); cv[6] = f2bf(cb[t].z); cv[7] = f2bf(cb[t].w);
            *(u16x8*)(x16 + (size_t)(base + t) * HDIM + l16 * 8) = cv;
        }
    }
    compute4(ca, cb, base, e, qa, qb, st);

    if (seg < B) finish_state(st, r_out + (size_t)seg * HDIM + l16 * 8);
}

// ---- passes 2,3: SLIM bf16 attention. Single online state, 2 rows/quarter/iter,
// depth-1 prefetch. Targeted <=64 VGPR so launch_bounds(256,8) gives 8 waves/SIMD
// (32 waves/CU, 2x the previous occupancy) for HBM latency hiding via TLP.
__global__ __launch_bounds__(256, 8) void k_attn_b16(const unsigned short* __restrict__ x16,
                                                     const float* __restrict__ q, int ldq,
                                                     const int* __restrict__ seg_start,
                                                     float* __restrict__ r_out, int ldr, int col_off,
                                                     int B, int rev) {
    int wave = threadIdx.x >> 6;
    int lane = threadIdx.x & 63;
    int l16 = lane & 15;
    int quarter = lane >> 4;
    int seg = seg_of_block(blockIdx.x, gridDim.x, rev, wave, quarter);
    int seg_c = min(seg, B - 1);
    int s = seg_start[seg_c], e = seg_start[seg_c + 1];
    if (seg >= B) { s = 0; e = 1; }  // safe dummy; result discarded

    const float* qrow = q + (size_t)seg_c * ldq + l16 * 8;
    vf4 qa = *(const vf4*)qrow;
    vf4 qb = *(const vf4*)(qrow + 4);

    int iters = (e - s + 1) >> 1;
    iters = max(iters, __shfl_xor(iters, 16, 64));
    iters = max(iters, __shfl_xor(iters, 32, 64));
    iters = max(iters, 1);

    float m = 0.f, d = 0.f;
    vf4 ra = {0.f, 0.f, 0.f, 0.f}, rb = {0.f, 0.f, 0.f, 0.f};

    u16x8 c0, c1;
    {
        int r0 = min(s, e - 1), r1 = min(s + 1, e - 1);
        c0 = *(const u16x8*)(x16 + (size_t)r0 * HDIM + l16 * 8);
        c1 = *(const u16x8*)(x16 + (size_t)r1 * HDIM + l16 * 8);
    }
    int base = s;
#pragma unroll 1
    for (int j = 1; j < iters; ++j) {
        int r0 = min(s + 2 * j, e - 1), r1 = min(s + 2 * j + 1, e - 1);
        u16x8 n0 = *(const u16x8*)(x16 + (size_t)r0 * HDIM + l16 * 8);
        u16x8 n1 = *(const u16x8*)(x16 + (size_t)r1 * HDIM + l16 * 8);
        vf4 xa0 = {bf2f(c0[0]), bf2f(c0[1]), bf2f(c0[2]), bf2f(c0[3])};
        vf4 xb0 = {bf2f(c0[4]), bf2f(c0[5]), bf2f(c0[6]), bf2f(c0[7])};
        vf4 xa1 = {bf2f(c1[0]), bf2f(c1[1]), bf2f(c1[2]), bf2f(c1[3])};
        vf4 xb1 = {bf2f(c1[4]), bf2f(c1[5]), bf2f(c1[6]), bf2f(c1[7])};
        float p0 = dot4(xa0, qa) + dot4(xb0, qb);
        float p1 = dot4(xa1, qa) + dot4(xb1, qb);
        SHFL16(p0) SHFL16(p1)
        if (base >= e) p0 = -1e30f;
        if (base + 1 >= e) p1 = -1e30f;
        UPD(m, d, ra, rb, p0, xa0, xb0)
        UPD(m, d, ra, rb, p1, xa1, xb1)
        c0 = n0; c1 = n1;
        base += 2;
    }
    {
        vf4 xa0 = {bf2f(c0[0]), bf2f(c0[1]), bf2f(c0[2]), bf2f(c0[3])};
        vf4 xb0 = {bf2f(c0[4]), bf2f(c0[5]), bf2f(c0[6]), bf2f(c0[7])};
        vf4 xa1 = {bf2f(c1[0]), bf2f(c1[1]), bf2f(c1[2]), bf2f(c1[3])};
        vf4 xb1 = {bf2f(c1[4]), bf2f(c1[5]), bf2f(c1[6]), bf2f(c1[7])};
        float p0 = dot4(xa0, qa) + dot4(xb0, qb);
        float p1 = dot4(xa1, qa) + dot4(xb1, qb);
        SHFL16(p0) SHFL16(p1)
        if (base >= e) p0 = -1e30f;
        if (base + 1 >= e) p1 = -1e30f;
        UPD(m, d, ra, rb, p0, xa0, xb0)
        UPD(m, d, ra, rb, p1, xa1, xb1)
    }
    if (seg < B) {
        float inv = (d > 0.0f) ? 1.0f / d : 0.0f;
        float* dst = r_out + (size_t)seg * ldr + col_off + l16 * 8;
        *(vf4*)dst = ra * inv;
        *(vf4*)(dst + 4) = rb * inv;
    }
}

// ---- step-1 GEMM + LSTM: K=128 (r only); gh0 folded into bias; c0 recomputed.
__global__ __launch_bounds__(256) void k_gemm_lstm1(const float* __restrict__ r_prev,
                                                    const float* __restrict__ Wc,
                                                    const float* __restrict__ gh0,
                                                    const float* __restrict__ b_ih,
                                                    const float* __restrict__ b_hh,
                                                    float* __restrict__ h_new,
                                                    float* __restrict__ c_new) {
    __shared__ float As[128 * TS];
    __shared__ float Ws[64 * TS];
    int ct = blockIdx.y;
    int rb = blockIdx.x * 128;
    int tid = threadIdx.x;
    int tx = tid & 15, ty = tid >> 4;
    float acc[8][4];
#pragma unroll
    for (int i = 0; i < 8; ++i)
#pragma unroll
        for (int j = 0; j < 4; ++j) acc[i][j] = 0.0f;

    for (int kc = 0; kc < 4; ++kc) {
        int kbase = kc * 32;
#pragma unroll
        for (int i = 0; i < 4; ++i) {
            int li = tid + i * 256;
            int row = li >> 3;
            int c4 = (li & 7) * 4;
            *(vf4*)&As[row * TS + c4] = *(const vf4*)(r_prev + (size_t)(rb + row) * HDIM + kbase + c4);
        }
#pragma unroll
        for (int i = 0; i < 2; ++i) {
            int li = tid + i * 256;
            int col = li >> 3;
            int c4 = (li & 7) * 4;
            int g = ct * 16 + (col & 15) + 128 * (col >> 4);
            *(vf4*)&Ws[col * TS + c4] = *(const vf4*)(Wc + (size_t)g * 256 + 128 + kbase + c4);
        }
        __syncthreads();
#pragma unroll
        for (int k = 0; k < 32; k += 4) {
            vf4 a[8], b[4];
#pragma unroll
            for (int i = 0; i < 8; ++i) a[i] = *(vf4*)&As[(ty + 16 * i) * TS + k];
#pragma unroll
            for (int j = 0; j < 4; ++j) b[j] = *(vf4*)&Ws[(tx + 16 * j) * TS + k];
#pragma unroll
            for (int i = 0; i < 8; ++i)
#pragma unroll
                for (int j = 0; j < 4; ++j) {
                    acc[i][j] += a[i].x * b[j].x + a[i].y * b[j].y +
                                 a[i].z * b[j].z + a[i].w * b[j].w;
                }
        }
        __syncthreads();
    }
    int hidx = ct * 16 + tx;
    float bi = b_ih[hidx] + b_hh[hidx] + gh0[hidx];
    float bf = b_ih[HDIM + hidx] + b_hh[HDIM + hidx] + gh0[HDIM + hidx];
    float bg = b_ih[2 * HDIM + hidx] + b_hh[2 * HDIM + hidx] + gh0[2 * HDIM + hidx];
    float bo = b_ih[3 * HDIM + hidx] + b_hh[3 * HDIM + hidx] + gh0[3 * HDIM + hidx];
    float bi0 = b_ih[hidx] + b_hh[hidx];
    float bg0 = b_ih[2 * HDIM + hidx] + b_hh[2 * HDIM + hidx];
    float c0 = sigm(bi0) * ftanh(bg0);
#pragma unroll
    for (int i = 0; i < 8; ++i) {
        int row = rb + ty + 16 * i;
        float gi = acc[i][0] + bi;
        float gf = acc[i][1] + bf;
        float gg = acc[i][2] + bg;
        float go = acc[i][3] + bo;
        float cn = sigm(gf) * c0 + sigm(gi) * ftanh(gg);
        float hn = sigm(go) * ftanh(cn);
        c_new[(size_t)row * HDIM + hidx] = cn;
        h_new[(size_t)row * HDIM + hidx] = hn;
    }
}

// ---- step-2 GEMM + LSTM: K=256 (h | r); h written only into out[:, :128].
__global__ __launch_bounds__(256) void k_gemm_lstm(const float* __restrict__ h_prev,
                                                   const float* __restrict__ r_prev,
                                                   const float* __restrict__ c_prev,
                                                   const float* __restrict__ Wc,
                                                   const float* __restrict__ b_ih,
                                                   const float* __restrict__ b_hh,
                                                   float* __restrict__ h_mirror) {
    __shared__ float As[128 * TS];
    __shared__ float Ws[64 * TS];
    int ct = blockIdx.y;
    int rb = blockIdx.x * 128;
    int tid = threadIdx.x;
    int tx = tid & 15, ty = tid >> 4;
    float acc[8][4];
#pragma unroll
    for (int i = 0; i < 8; ++i)
#pragma unroll
        for (int j = 0; j < 4; ++j) acc[i][j] = 0.0f;

    for (int kc = 0; kc < 8; ++kc) {
        const float* src = (kc < 4) ? h_prev : r_prev;
        int kbase = (kc & 3) * 32;
#pragma unroll
        for (int i = 0; i < 4; ++i) {
            int li = tid + i * 256;
            int row = li >> 3;
            int c4 = (li & 7) * 4;
            *(vf4*)&As[row * TS + c4] = *(const vf4*)(src + (size_t)(rb + row) * HDIM + kbase + c4);
        }
#pragma unroll
        for (int i = 0; i < 2; ++i) {
            int li = tid + i * 256;
            int col = li >> 3;
            int c4 = (li & 7) * 4;
            int g = ct * 16 + (col & 15) + 128 * (col >> 4);
            *(vf4*)&Ws[col * TS + c4] = *(const vf4*)(Wc + (size_t)g * 256 + kc * 32 + c4);
        }
        __syncthreads();
#pragma unroll
        for (int k = 0; k < 32; k += 4) {
            vf4 a[8], b[4];
#pragma unroll
            for (int i = 0; i < 8; ++i) a[i] = *(vf4*)&As[(ty + 16 * i) * TS + k];
#pragma unroll
            for (int j = 0; j < 4; ++j) b[j] = *(vf4*)&Ws[(tx + 16 * j) * TS + k];
#pragma unroll
            for (int i = 0; i < 8; ++i)
#pragma unroll
                for (int j = 0; j < 4; ++j) {
                    acc[i][j] += a[i].x * b[j].x + a[i].y * b[j].y +
                                 a[i].z * b[j].z + a[i].w * b[j].w;
                }
        }
        __syncthreads();
    }
    int hidx = ct * 16 + tx;
    float bi = b_ih[hidx] + b_hh[hidx];
    float bf = b_ih[HDIM + hidx] + b_hh[HDIM + hidx];
    float bg = b_ih[2 * HDIM + hidx] + b_hh[2 * HDIM + hidx];
    float bo = b_ih[3 * HDIM + hidx] + b_hh[3 * HDIM + hidx];
#pragma unroll
    for (int i = 0; i < 8; ++i) {
        int row = rb + ty + 16 * i;
        float gi = acc[i][0] + bi;
        float gf = acc[i][1] + bf;
        float gg = acc[i][2] + bg;
        float go = acc[i][3] + bo;
        float cp = c_prev[(size_t)row * HDIM + hidx];
        float cn = sigm(gf) * cp + sigm(gi) * ftanh(gg);
        float hn = sigm(go) * ftanh(cn);
        h_mirror[(size_t)row * 2 * HDIM + hidx] = hn;
    }
}

extern "C" void kernel_launch(void* const* d_in, const int* in_sizes, int n_in,
                              void* d_out, int out_size, void* d_ws, size_t ws_size,
                              hipStream_t stream) {
    const float* x = (const float*)d_in[0];
    const int* batch_vec = (const int*)d_in[1];
    const float* W_ih = (const float*)d_in[2];
    const float* W_hh = (const float*)d_in[3];
    const float* b_ih = (const float*)d_in[4];
    const float* b_hh = (const float*)d_in[5];
    float* out = (float*)d_out;

    int N = in_sizes[1];
    int B = out_size / (2 * HDIM);

    char* ws = (char*)d_ws;
    float* Wc = (float*)ws;   ws += (size_t)G4 * 2 * HDIM * 4;
    float* gh0 = (float*)ws;  ws += (size_t)G4 * 4;
    float* h_b = (float*)ws;  ws += (size_t)B * HDIM * 4;
    float* cbuf = (float*)ws; ws += (size_t)B * HDIM * 4;
    float* rbuf = (float*)ws; ws += (size_t)B * HDIM * 4;
    int* seg = (int*)ws;      ws += (size_t)(B + 1) * 4;
    ws = (char*)(((size_t)ws + 255) & ~(size_t)255);
    unsigned short* x16 = (unsigned short*)ws;  // N*128*2 = 256 MB

    k_setup<<<512, 256, 0, stream>>>(W_ih, W_hh, b_ih, b_hh, batch_vec, N, B, Wc, seg, gh0);

    dim3 ggrid(B / 128, 8);
    int ablk = (B + 15) / 16;  // quarter-per-segment: 16 segments per block
    k_attn_cvt<<<ablk, 256, 0, stream>>>(x, x16, b_ih, b_hh, seg, rbuf, B);
    k_gemm_lstm1<<<ggrid, 256, 0, stream>>>(rbuf, Wc, gh0, b_ih, b_hh, h_b, cbuf);
    k_attn_b16<<<ablk, 256, 0, stream>>>(x16, h_b, HDIM, seg, rbuf, HDIM, 0, B, 1);
    k_gemm_lstm<<<ggrid, 256, 0, stream>>>(h_b, rbuf, cbuf, Wc, b_ih, b_hh, out);
    k_attn_b16<<<ablk, 256, 0, stream>>>(x16, out, 2 * HDIM, seg, out, 2 * HDIM, HDIM, B, 0);
}

// Round 14
// 456.776 us; speedup vs baseline: 1.0470x; 1.0470x over previous
//
#include <hip/hip_runtime.h>
#include <math.h>

#define HDIM 128
#define G4 512  // 4*H
#define TS 36   // GEMM LDS row stride (floats)

typedef float vf4 __attribute__((ext_vector_type(4)));
typedef unsigned short u16x8 __attribute__((ext_vector_type(8)));

__device__ __forceinline__ float sigm(float v) { return 1.0f / (1.0f + __expf(-v)); }
__device__ __forceinline__ float ftanh(float v) {
    return 1.0f - 2.0f / (__expf(2.0f * v) + 1.0f);
}
__device__ __forceinline__ float dot4(vf4 a, vf4 b) {
    return a.x * b.x + a.y * b.y + a.z * b.z + a.w * b.w;
}
__device__ __forceinline__ vf4 ldnt4(const float* p) {
    return __builtin_nontemporal_load((const vf4*)p);
}
__device__ __forceinline__ unsigned short f2bf(float f) {  // RTNE
    unsigned u = __float_as_uint(f);
    u += 0x7fff + ((u >> 16) & 1);
    return (unsigned short)(u >> 16);
}
__device__ __forceinline__ float bf2f(unsigned short h) {
    return __uint_as_float(((unsigned)h) << 16);
}

#define SHFL16(p_)                  \
    p_ += __shfl_xor(p_, 1, 64);    \
    p_ += __shfl_xor(p_, 2, 64);    \
    p_ += __shfl_xor(p_, 4, 64);    \
    p_ += __shfl_xor(p_, 8, 64);

// ---- setup: Wc prep + segment starts + gh0 (= Wc_h . h0, h0 from biases)
__global__ __launch_bounds__(256) void k_setup(const float* __restrict__ W_ih,
                                               const float* __restrict__ W_hh,
                                               const float* __restrict__ b_ih,
                                               const float* __restrict__ b_hh,
                                               const int* __restrict__ batch_vec, int N, int B,
                                               float* __restrict__ Wc, int* __restrict__ seg_start,
                                               float* __restrict__ gh0) {
    __shared__ float h0s[HDIM];
    int t = blockIdx.x * 256 + threadIdx.x;
    if (blockIdx.x < 2) {
        if (threadIdx.x < HDIM) {
            int hid = threadIdx.x;
            float bi = b_ih[hid] + b_hh[hid];
            float bg = b_ih[2 * HDIM + hid] + b_hh[2 * HDIM + hid];
            float bo = b_ih[3 * HDIM + hid] + b_hh[3 * HDIM + hid];
            float c0 = sigm(bi) * ftanh(bg);
            h0s[hid] = sigm(bo) * ftanh(c0);
        }
        __syncthreads();
        if (t < G4) {
            float s = 0.0f;
#pragma unroll
            for (int k = 0; k < HDIM; k += 4) {
                vf4 wi = *(const vf4*)(W_ih + (size_t)t * 256 + k);
                vf4 wh = *(const vf4*)(W_hh + (size_t)t * HDIM + k);
                s += (wi.x + wh.x) * h0s[k] + (wi.y + wh.y) * h0s[k + 1] +
                     (wi.z + wh.z) * h0s[k + 2] + (wi.w + wh.w) * h0s[k + 3];
            }
            gh0[t] = s;
        }
    }
    if (t < G4 * 2 * HDIM) {
        int g = t >> 8;
        int k = t & 255;
        float w = W_ih[g * 256 + k];
        if (k < HDIM) w += W_hh[g * HDIM + k];
        Wc[t] = w;
    }
    if (t <= B) {
        int lo = 0, hi = N;
        while (lo < hi) {
            int mid = (lo + hi) >> 1;
            if (batch_vec[mid] < t) lo = mid + 1; else hi = mid;
        }
        seg_start[t] = lo;
    }
}

// segment geometry for quarter-per-segment layout (4 segs/wave, 16/block)
__device__ __forceinline__ int seg_of_block(int bid, int nblk, int rev, int wave, int quarter) {
    int q8 = nblk >> 3, r8 = nblk & 7;
    int xcd = bid & 7, pos = bid >> 3;
    int nb = (xcd < r8 ? xcd * (q8 + 1) : r8 * (q8 + 1) + (xcd - r8) * q8) + pos;
    if (rev) nb = nblk - 1 - nb;
    return nb * 16 + wave * 4 + quarter;
}

// ---- pass 1: fp32 x attention (no-max softmax: exp(e) directly — logits bounded)
// + fused bf16 conversion; q0 from biases. Quarter-per-segment, depth-1 prefetch.
__global__ __launch_bounds__(256) void k_attn_cvt(const float* __restrict__ x,
                                                  unsigned short* __restrict__ x16,
                                                  const float* __restrict__ b_ih,
                                                  const float* __restrict__ b_hh,
                                                  const int* __restrict__ seg_start,
                                                  float* __restrict__ r_out, int B) {
    int wave = threadIdx.x >> 6;
    int lane = threadIdx.x & 63;
    int l16 = lane & 15;
    int quarter = lane >> 4;
    int seg = seg_of_block(blockIdx.x, gridDim.x, 0, wave, quarter);
    int seg_c = min(seg, B - 1);
    int s = seg_start[seg_c], e = seg_start[seg_c + 1];
    if (seg >= B) { s = 0; e = 1; }

    vf4 qa, qb;
    {  // q0 from biases (step-0 LSTM with h=c=0)
        int c = l16 * 8;
        vf4 bi0 = *(const vf4*)(b_ih + c) + *(const vf4*)(b_hh + c);
        vf4 bi1 = *(const vf4*)(b_ih + c + 4) + *(const vf4*)(b_hh + c + 4);
        vf4 bg0 = *(const vf4*)(b_ih + 2 * HDIM + c) + *(const vf4*)(b_hh + 2 * HDIM + c);
        vf4 bg1 = *(const vf4*)(b_ih + 2 * HDIM + c + 4) + *(const vf4*)(b_hh + 2 * HDIM + c + 4);
        vf4 bo0 = *(const vf4*)(b_ih + 3 * HDIM + c) + *(const vf4*)(b_hh + 3 * HDIM + c);
        vf4 bo1 = *(const vf4*)(b_ih + 3 * HDIM + c + 4) + *(const vf4*)(b_hh + 3 * HDIM + c + 4);
#pragma unroll
        for (int j = 0; j < 4; ++j) {
            float c0 = sigm(bi0[j]) * ftanh(bg0[j]);
            qa[j] = sigm(bo0[j]) * ftanh(c0);
            float c1 = sigm(bi1[j]) * ftanh(bg1[j]);
            qb[j] = sigm(bo1[j]) * ftanh(c1);
        }
    }

    int iters = (e - s + 3) >> 2;
    iters = max(iters, __shfl_xor(iters, 16, 64));
    iters = max(iters, __shfl_xor(iters, 32, 64));
    iters = max(iters, 1);

    float d = 0.f;
    vf4 ra = {0.f, 0.f, 0.f, 0.f}, rb = {0.f, 0.f, 0.f, 0.f};

    vf4 ca[4], cb[4];
#pragma unroll
    for (int t = 0; t < 4; ++t) {
        int rl = max(min(s + t, e - 1), 0);
        const float* xr = x + (size_t)rl * HDIM + l16 * 8;
        ca[t] = ldnt4(xr);
        cb[t] = ldnt4(xr + 4);
    }
    int base = s;
#pragma unroll 1
    for (int j = 1; j < iters; ++j) {
        vf4 na[4], nb[4];
#pragma unroll
        for (int t = 0; t < 4; ++t) {
            int rl = max(min(s + 4 * j + t, e - 1), 0);
            const float* xr = x + (size_t)rl * HDIM + l16 * 8;
            na[t] = ldnt4(xr);
            nb[t] = ldnt4(xr + 4);
        }
#pragma unroll
        for (int t = 0; t < 4; ++t) {
            if (base + t < e) {
                u16x8 cv;
                cv[0] = f2bf(ca[t].x); cv[1] = f2bf(ca[t].y); cv[2] = f2bf(ca[t].z); cv[3] = f2bf(ca[t].w);
                cv[4] = f2bf(cb[t].x); cv[5] = f2bf(cb[t].y); cv[6] = f2bf(cb[t].z); cv[7] = f2bf(cb[t].w);
                *(u16x8*)(x16 + (size_t)(base + t) * HDIM + l16 * 8) = cv;
            }
            float p = dot4(ca[t], qa) + dot4(cb[t], qb);
            SHFL16(p)
            float w = (base + t < e) ? __expf(p) : 0.f;
            d += w;
            ra += w * ca[t];
            rb += w * cb[t];
        }
#pragma unroll
        for (int t = 0; t < 4; ++t) { ca[t] = na[t]; cb[t] = nb[t]; }
        base += 4;
    }
#pragma unroll
    for (int t = 0; t < 4; ++t) {
        if (base + t < e) {
            u16x8 cv;
            cv[0] = f2bf(ca[t].x); cv[1] = f2bf(ca[t].y); cv[2] = f2bf(ca[t].z); cv[3] = f2bf(ca[t].w);
            cv[4] = f2bf(cb[t].x); cv[5] = f2bf(cb[t].y); cv[6] = f2bf(cb[t].z); cv[7] = f2bf(cb[t].w);
            *(u16x8*)(x16 + (size_t)(base + t) * HDIM + l16 * 8) = cv;
        }
        float p = dot4(ca[t], qa) + dot4(cb[t], qb);
        SHFL16(p)
        float w = (base + t < e) ? __expf(p) : 0.f;
        d += w;
        ra += w * ca[t];
        rb += w * cb[t];
    }

    if (seg < B) {
        float inv = (d > 0.0f) ? 1.0f / d : 0.0f;
        float* dst = r_out + (size_t)seg * HDIM + l16 * 8;
        *(vf4*)dst = ra * inv;
        *(vf4*)(dst + 4) = rb * inv;
    }
}

// ---- passes 2,3: bf16 attention, no-max softmax (plain-sum accumulators, no
// serial chain, no merge). Quarter-per-segment, 4 rows/iter, depth-1 prefetch.
__global__ __launch_bounds__(256) void k_attn_b16(const unsigned short* __restrict__ x16,
                                                  const float* __restrict__ q, int ldq,
                                                  const int* __restrict__ seg_start,
                                                  float* __restrict__ r_out, int ldr, int col_off,
                                                  int B, int rev) {
    int wave = threadIdx.x >> 6;
    int lane = threadIdx.x & 63;
    int l16 = lane & 15;
    int quarter = lane >> 4;
    int seg = seg_of_block(blockIdx.x, gridDim.x, rev, wave, quarter);
    int seg_c = min(seg, B - 1);
    int s = seg_start[seg_c], e = seg_start[seg_c + 1];
    if (seg >= B) { s = 0; e = 1; }

    const float* qrow = q + (size_t)seg_c * ldq + l16 * 8;
    vf4 qa = *(const vf4*)qrow;
    vf4 qb = *(const vf4*)(qrow + 4);

    int iters = (e - s + 3) >> 2;
    iters = max(iters, __shfl_xor(iters, 16, 64));
    iters = max(iters, __shfl_xor(iters, 32, 64));
    iters = max(iters, 1);

    float d = 0.f;
    vf4 ra = {0.f, 0.f, 0.f, 0.f}, rb = {0.f, 0.f, 0.f, 0.f};

    u16x8 cur[4];
#pragma unroll
    for (int t = 0; t < 4; ++t) {
        int rl = max(min(s + t, e - 1), 0);
        cur[t] = *(const u16x8*)(x16 + (size_t)rl * HDIM + l16 * 8);
    }
    int base = s;
#pragma unroll 1
    for (int j = 1; j < iters; ++j) {
        u16x8 nxt[4];
#pragma unroll
        for (int t = 0; t < 4; ++t) {
            int rl = max(min(s + 4 * j + t, e - 1), 0);
            nxt[t] = *(const u16x8*)(x16 + (size_t)rl * HDIM + l16 * 8);
        }
#pragma unroll
        for (int t = 0; t < 4; ++t) {
            vf4 xa = {bf2f(cur[t][0]), bf2f(cur[t][1]), bf2f(cur[t][2]), bf2f(cur[t][3])};
            vf4 xb = {bf2f(cur[t][4]), bf2f(cur[t][5]), bf2f(cur[t][6]), bf2f(cur[t][7])};
            float p = dot4(xa, qa) + dot4(xb, qb);
            SHFL16(p)
            float w = (base + t < e) ? __expf(p) : 0.f;
            d += w;
            ra += w * xa;
            rb += w * xb;
        }
#pragma unroll
        for (int t = 0; t < 4; ++t) cur[t] = nxt[t];
        base += 4;
    }
#pragma unroll
    for (int t = 0; t < 4; ++t) {
        vf4 xa = {bf2f(cur[t][0]), bf2f(cur[t][1]), bf2f(cur[t][2]), bf2f(cur[t][3])};
        vf4 xb = {bf2f(cur[t][4]), bf2f(cur[t][5]), bf2f(cur[t][6]), bf2f(cur[t][7])};
        float p = dot4(xa, qa) + dot4(xb, qb);
        SHFL16(p)
        float w = (base + t < e) ? __expf(p) : 0.f;
        d += w;
        ra += w * xa;
        rb += w * xb;
    }

    if (seg < B) {
        float inv = (d > 0.0f) ? 1.0f / d : 0.0f;
        float* dst = r_out + (size_t)seg * ldr + col_off + l16 * 8;
        *(vf4*)dst = ra * inv;
        *(vf4*)(dst + 4) = rb * inv;
    }
}

// ---- step-1 GEMM + LSTM: K=128 (r only); gh0 folded into bias; c0 recomputed.
__global__ __launch_bounds__(256) void k_gemm_lstm1(const float* __restrict__ r_prev,
                                                    const float* __restrict__ Wc,
                                                    const float* __restrict__ gh0,
                                                    const float* __restrict__ b_ih,
                                                    const float* __restrict__ b_hh,
                                                    float* __restrict__ h_new,
                                                    float* __restrict__ c_new) {
    __shared__ float As[128 * TS];
    __shared__ float Ws[64 * TS];
    int ct = blockIdx.y;
    int rb = blockIdx.x * 128;
    int tid = threadIdx.x;
    int tx = tid & 15, ty = tid >> 4;
    float acc[8][4];
#pragma unroll
    for (int i = 0; i < 8; ++i)
#pragma unroll
        for (int j = 0; j < 4; ++j) acc[i][j] = 0.0f;

    for (int kc = 0; kc < 4; ++kc) {
        int kbase = kc * 32;
#pragma unroll
        for (int i = 0; i < 4; ++i) {
            int li = tid + i * 256;
            int row = li >> 3;
            int c4 = (li & 7) * 4;
            *(vf4*)&As[row * TS + c4] = *(const vf4*)(r_prev + (size_t)(rb + row) * HDIM + kbase + c4);
        }
#pragma unroll
        for (int i = 0; i < 2; ++i) {
            int li = tid + i * 256;
            int col = li >> 3;
            int c4 = (li & 7) * 4;
            int g = ct * 16 + (col & 15) + 128 * (col >> 4);
            *(vf4*)&Ws[col * TS + c4] = *(const vf4*)(Wc + (size_t)g * 256 + 128 + kbase + c4);
        }
        __syncthreads();
#pragma unroll
        for (int k = 0; k < 32; k += 4) {
            vf4 a[8], b[4];
#pragma unroll
            for (int i = 0; i < 8; ++i) a[i] = *(vf4*)&As[(ty + 16 * i) * TS + k];
#pragma unroll
            for (int j = 0; j < 4; ++j) b[j] = *(vf4*)&Ws[(tx + 16 * j) * TS + k];
#pragma unroll
            for (int i = 0; i < 8; ++i)
#pragma unroll
                for (int j = 0; j < 4; ++j) {
                    acc[i][j] += a[i].x * b[j].x + a[i].y * b[j].y +
                                 a[i].z * b[j].z + a[i].w * b[j].w;
                }
        }
        __syncthreads();
    }
    int hidx = ct * 16 + tx;
    float bi = b_ih[hidx] + b_hh[hidx] + gh0[hidx];
    float bf = b_ih[HDIM + hidx] + b_hh[HDIM + hidx] + gh0[HDIM + hidx];
    float bg = b_ih[2 * HDIM + hidx] + b_hh[2 * HDIM + hidx] + gh0[2 * HDIM + hidx];
    float bo = b_ih[3 * HDIM + hidx] + b_hh[3 * HDIM + hidx] + gh0[3 * HDIM + hidx];
    float bi0 = b_ih[hidx] + b_hh[hidx];
    float bg0 = b_ih[2 * HDIM + hidx] + b_hh[2 * HDIM + hidx];
    float c0 = sigm(bi0) * ftanh(bg0);
#pragma unroll
    for (int i = 0; i < 8; ++i) {
        int row = rb + ty + 16 * i;
        float gi = acc[i][0] + bi;
        float gf = acc[i][1] + bf;
        float gg = acc[i][2] + bg;
        float go = acc[i][3] + bo;
        float cn = sigm(gf) * c0 + sigm(gi) * ftanh(gg);
        float hn = sigm(go) * ftanh(cn);
        c_new[(size_t)row * HDIM + hidx] = cn;
        h_new[(size_t)row * HDIM + hidx] = hn;
    }
}

// ---- step-2 GEMM + LSTM: K=256 (h | r); h written only into out[:, :128].
__global__ __launch_bounds__(256) void k_gemm_lstm(const float* __restrict__ h_prev,
                                                   const float* __restrict__ r_prev,
                                                   const float* __restrict__ c_prev,
                                                   const float* __restrict__ Wc,
                                                   const float* __restrict__ b_ih,
                                                   const float* __restrict__ b_hh,
                                                   float* __restrict__ h_mirror) {
    __shared__ float As[128 * TS];
    __shared__ float Ws[64 * TS];
    int ct = blockIdx.y;
    int rb = blockIdx.x * 128;
    int tid = threadIdx.x;
    int tx = tid & 15, ty = tid >> 4;
    float acc[8][4];
#pragma unroll
    for (int i = 0; i < 8; ++i)
#pragma unroll
        for (int j = 0; j < 4; ++j) acc[i][j] = 0.0f;

    for (int kc = 0; kc < 8; ++kc) {
        const float* src = (kc < 4) ? h_prev : r_prev;
        int kbase = (kc & 3) * 32;
#pragma unroll
        for (int i = 0; i < 4; ++i) {
            int li = tid + i * 256;
            int row = li >> 3;
            int c4 = (li & 7) * 4;
            *(vf4*)&As[row * TS + c4] = *(const vf4*)(src + (size_t)(rb + row) * HDIM + kbase + c4);
        }
#pragma unroll
        for (int i = 0; i < 2; ++i) {
            int li = tid + i * 256;
            int col = li >> 3;
            int c4 = (li & 7) * 4;
            int g = ct * 16 + (col & 15) + 128 * (col >> 4);
            *(vf4*)&Ws[col * TS + c4] = *(const vf4*)(Wc + (size_t)g * 256 + kc * 32 + c4);
        }
        __syncthreads();
#pragma unroll
        for (int k = 0; k < 32; k += 4) {
            vf4 a[8], b[4];
#pragma unroll
            for (int i = 0; i < 8; ++i) a[i] = *(vf4*)&As[(ty + 16 * i) * TS + k];
#pragma unroll
            for (int j = 0; j < 4; ++j) b[j] = *(vf4*)&Ws[(tx + 16 * j) * TS + k];
#pragma unroll
            for (int i = 0; i < 8; ++i)
#pragma unroll
                for (int j = 0; j < 4; ++j) {
                    acc[i][j] += a[i].x * b[j].x + a[i].y * b[j].y +
                                 a[i].z * b[j].z + a[i].w * b[j].w;
                }
        }
        __syncthreads();
    }
    int hidx = ct * 16 + tx;
    float bi = b_ih[hidx] + b_hh[hidx];
    float bf = b_ih[HDIM + hidx] + b_hh[HDIM + hidx];
    float bg = b_ih[2 * HDIM + hidx] + b_hh[2 * HDIM + hidx];
    float bo = b_ih[3 * HDIM + hidx] + b_hh[3 * HDIM + hidx];
#pragma unroll
    for (int i = 0; i < 8; ++i) {
        int row = rb + ty + 16 * i;
        float gi = acc[i][0] + bi;
        float gf = acc[i][1] + bf;
        float gg = acc[i][2] + bg;
        float go = acc[i][3] + bo;
        float cp = c_prev[(size_t)row * HDIM + hidx];
        float cn = sigm(gf) * cp + sigm(gi) * ftanh(gg);
        float hn = sigm(go) * ftanh(cn);
        h_mirror[(size_t)row * 2 * HDIM + hidx] = hn;
    }
}

extern "C" void kernel_launch(void* const* d_in, const int* in_sizes, int n_in,
                              void* d_out, int out_size, void* d_ws, size_t ws_size,
                              hipStream_t stream) {
    const float* x = (const float*)d_in[0];
    const int* batch_vec = (const int*)d_in[1];
    const float* W_ih = (const float*)d_in[2];
    const float* W_hh = (const float*)d_in[3];
    const float* b_ih = (const float*)d_in[4];
    const float* b_hh = (const float*)d_in[5];
    float* out = (float*)d_out;

    int N = in_sizes[1];
    int B = out_size / (2 * HDIM);

    char* ws = (char*)d_ws;
    float* Wc = (float*)ws;   ws += (size_t)G4 * 2 * HDIM * 4;
    float* gh0 = (float*)ws;  ws += (size_t)G4 * 4;
    float* h_b = (float*)ws;  ws += (size_t)B * HDIM * 4;
    float* cbuf = (float*)ws; ws += (size_t)B * HDIM * 4;
    float* rbuf = (float*)ws; ws += (size_t)B * HDIM * 4;
    int* seg = (int*)ws;      ws += (size_t)(B + 1) * 4;
    ws = (char*)(((size_t)ws + 255) & ~(size_t)255);
    unsigned short* x16 = (unsigned short*)ws;  // N*128*2 = 256 MB

    k_setup<<<512, 256, 0, stream>>>(W_ih, W_hh, b_ih, b_hh, batch_vec, N, B, Wc, seg, gh0);

    dim3 ggrid(B / 128, 8);
    int ablk = (B + 15) / 16;  // quarter-per-segment: 16 segments per block
    k_attn_cvt<<<ablk, 256, 0, stream>>>(x, x16, b_ih, b_hh, seg, rbuf, B);
    k_gemm_lstm1<<<ggrid, 256, 0, stream>>>(rbuf, Wc, gh0, b_ih, b_hh, h_b, cbuf);
    k_attn_b16<<<ablk, 256, 0, stream>>>(x16, h_b, HDIM, seg, rbuf, HDIM, 0, B, 1);
    k_gemm_lstm<<<ggrid, 256, 0, stream>>>(h_b, rbuf, cbuf, Wc, b_ih, b_hh, out);
    k_attn_b16<<<ablk, 256, 0, stream>>>(x16, out, 2 * HDIM, seg, out, 2 * HDIM, HDIM, B, 0);
}